// Round 1
// 241.770 us; speedup vs baseline: 1.0122x; 1.0122x over previous
//
#include <hip/hip_runtime.h>

// FeedForwardQuantum fused: out = q(x@w1^T + b1) @ w2^T + b2
// Quantum layer reduced analytically (Clifford circuit):
//   c_i = cos(h_i)
//   q0=c0, q1=c1, q2=c0c2, q3=c1c3, q4=c0c2c4, q5=c1c3c5,
//   q6=c0c2c4c6, q7=c0c1c2c3c4c5c6c7
// = parity-chain prefix products; q7 = (even chain)*(odd chain).
//
// This revision: phase 1 processes 4 rows per iteration (4 loads in flight,
// 4 interleaved butterfly chains, 4x w1 register reuse), TILE 16->32,
// launch_bounds relaxed to 128 VGPR, non-temporal output stores.

typedef float f4 __attribute__((ext_vector_type(4)));

constexpr int THREADS = 256;
constexpr int TILE    = 32;          // rows per block
constexpr int RPI     = 4;           // rows per phase-1 iteration
constexpr int NGROUP  = TILE / RPI;  // 8 iterations
constexpr int E       = 1024;
constexpr int R_TOTAL = 8 * 4096;    // 32768 rows -> 1024 blocks -> 4 blocks/CU

static_assert(TILE * 8 == THREADS, "phase 2 uses all threads");

__global__ __launch_bounds__(THREADS, 4)   // 128 VGPR cap: no AGPR spill,
void ffq_kernel(const float* __restrict__ x,   // 4 waves/SIMD occupancy
                const float* __restrict__ w1,
                const float* __restrict__ b1,
                const float* __restrict__ w2,
                const float* __restrict__ b2,
                float* __restrict__ out)
{
    __shared__ float part[TILE][33];            // stride 33: conflict-free
    __shared__ __align__(16) float qsh[TILE][8];
    __shared__ float b1s[8];

    const int t    = threadIdx.x;
    const int lane = t & 63;
    const int wid  = t >> 6;
    const int c0   = t * 4;                     // this thread's 4 columns of E

    if (t < 8) b1s[t] = b1[t];

    // w1 slice in registers: w1[f][c0..c0+3]  (dead after phase 1)
    f4 w1r[8];
#pragma unroll
    for (int f = 0; f < 8; ++f)
        w1r[f] = *(const f4*)(w1 + f * E + c0);

    const int row0 = blockIdx.x * TILE;
    const float* xp = x + (size_t)row0 * E + c0;

    // ---------------- phase 1: h partials + in-wave butterfly ----------------
    // 4 rows per iteration: 4 independent loads in flight, 4 independent
    // butterfly chains interleaved per stage (ILP over the DS pipe).
    f4 cur[RPI];
#pragma unroll
    for (int r = 0; r < RPI; ++r)
        cur[r] = *(const f4*)(xp + (size_t)r * E);

#pragma unroll
    for (int g = 0; g < NGROUP; ++g) {
        f4 xc[RPI];
#pragma unroll
        for (int r = 0; r < RPI; ++r) xc[r] = cur[r];

        // issue next group's loads before any compute: 8 loads in flight peak
        if (g + 1 < NGROUP) {
#pragma unroll
            for (int r = 0; r < RPI; ++r)
                cur[r] = *(const f4*)(xp + (size_t)((g + 1) * RPI + r) * E);
        }

        float h[RPI][8];
#pragma unroll
        for (int r = 0; r < RPI; ++r)
#pragma unroll
            for (int f = 0; f < 8; ++f)
                h[r][f] = xc[r].x * w1r[f].x + xc[r].y * w1r[f].y
                        + xc[r].z * w1r[f].z + xc[r].w * w1r[f].w;

        // multi-value butterfly: 8 sums across 64 lanes, 6 xor steps.
        // After step 3 lane L holds f = bitrev3(L&7); steps 4-6 all-reduce.
        // All 4 rows' chains interleaved per stage -> 4x ILP on DS latency.
        {   const bool hb = lane & 1;
#pragma unroll
            for (int r = 0; r < RPI; ++r) {
                float s0 = hb ? h[r][0] : h[r][4];
                float s1 = hb ? h[r][1] : h[r][5];
                float s2 = hb ? h[r][2] : h[r][6];
                float s3 = hb ? h[r][3] : h[r][7];
                s0 = __shfl_xor(s0, 1); s1 = __shfl_xor(s1, 1);
                s2 = __shfl_xor(s2, 1); s3 = __shfl_xor(s3, 1);
                h[r][0] = (hb ? h[r][4] : h[r][0]) + s0;
                h[r][1] = (hb ? h[r][5] : h[r][1]) + s1;
                h[r][2] = (hb ? h[r][6] : h[r][2]) + s2;
                h[r][3] = (hb ? h[r][7] : h[r][3]) + s3;
            }
        }
        {   const bool hb = lane & 2;
#pragma unroll
            for (int r = 0; r < RPI; ++r) {
                float s0 = hb ? h[r][0] : h[r][2];
                float s1 = hb ? h[r][1] : h[r][3];
                s0 = __shfl_xor(s0, 2); s1 = __shfl_xor(s1, 2);
                h[r][0] = (hb ? h[r][2] : h[r][0]) + s0;
                h[r][1] = (hb ? h[r][3] : h[r][1]) + s1;
            }
        }
        float v[RPI];
        {   const bool hb = lane & 4;
#pragma unroll
            for (int r = 0; r < RPI; ++r) {
                float s0 = hb ? h[r][0] : h[r][1];
                s0 = __shfl_xor(s0, 4);
                v[r] = (hb ? h[r][1] : h[r][0]) + s0;
            }
        }
#pragma unroll
        for (int r = 0; r < RPI; ++r) v[r] += __shfl_xor(v[r], 8);
#pragma unroll
        for (int r = 0; r < RPI; ++r) v[r] += __shfl_xor(v[r], 16);
#pragma unroll
        for (int r = 0; r < RPI; ++r) v[r] += __shfl_xor(v[r], 32);

        if (lane < 8) {
            const int f = ((lane & 1) << 2) | (lane & 2) | ((lane >> 2) & 1);
#pragma unroll
            for (int r = 0; r < RPI; ++r)
                part[g * RPI + r][f * 4 + wid] = v[r];
        }
    }
    __syncthreads();   // barrier 1 of 2

    // ---------------- phase 2: q-finish (all 256 threads: 32 rows x 8 f) ----
    {
        const int r = t >> 3;
        const int f = t & 7;
        const float hq = part[r][f * 4 + 0] + part[r][f * 4 + 1]
                       + part[r][f * 4 + 2] + part[r][f * 4 + 3] + b1s[f];
        float p = __cosf(hq);
        float u = __shfl_up(p, 2, 8); if (f >= 2) p *= u;
        u = __shfl_up(p, 4, 8);       if (f >= 4) p *= u;
        const float p6 = __shfl(p, 6, 8);   // even-chain full product
        if (f == 7) p *= p6;
        qsh[r][f] = p;
    }

    // w2/b2 register loads here: latency overlaps q-finish + barrier, and
    // keeps them out of phase-1's register peak (w1r regs now dead).
    float w2a[4][8];
#pragma unroll
    for (int j = 0; j < 4; ++j) {
        const f4 lo = *(const f4*)(w2 + (size_t)(c0 + j) * 8);
        const f4 hi = *(const f4*)(w2 + (size_t)(c0 + j) * 8 + 4);
        w2a[j][0] = lo.x; w2a[j][1] = lo.y; w2a[j][2] = lo.z; w2a[j][3] = lo.w;
        w2a[j][4] = hi.x; w2a[j][5] = hi.y; w2a[j][6] = hi.z; w2a[j][7] = hi.w;
    }
    const f4 b2v = *(const f4*)(b2 + c0);

    __syncthreads();   // barrier 2 of 2

    // ---------------- phase 3: out = q @ w2^T + b2 ----------------
    // Non-temporal stores: out is write-once/never-read -> keep it out of
    // L2/L3 so x (134 MB) stays L3-resident across dispatches.
#pragma unroll
    for (int s = 0; s < TILE; ++s) {
        const f4 qlo = *(const f4*)(&qsh[s][0]);   // broadcast reads
        const f4 qhi = *(const f4*)(&qsh[s][4]);
        const float qv[8] = {qlo.x, qlo.y, qlo.z, qlo.w,
                             qhi.x, qhi.y, qhi.z, qhi.w};
        f4 o = b2v;
#pragma unroll
        for (int f = 0; f < 8; ++f) {
            o.x += qv[f] * w2a[0][f];
            o.y += qv[f] * w2a[1][f];
            o.z += qv[f] * w2a[2][f];
            o.w += qv[f] * w2a[3][f];
        }
        __builtin_nontemporal_store(o, (f4*)(out + (size_t)(row0 + s) * E + c0));
    }
}

extern "C" void kernel_launch(void* const* d_in, const int* in_sizes, int n_in,
                              void* d_out, int out_size, void* d_ws, size_t ws_size,
                              hipStream_t stream)
{
    const float* x  = (const float*)d_in[0];
    const float* w1 = (const float*)d_in[1];
    const float* b1 = (const float*)d_in[2];
    const float* w2 = (const float*)d_in[3];
    const float* b2 = (const float*)d_in[4];
    float* out = (float*)d_out;

    ffq_kernel<<<dim3(R_TOTAL / TILE), THREADS, 0, stream>>>(x, w1, b1, w2, b2, out);
}